// Round 2
// baseline (209.797 us; speedup 1.0000x reference)
//
#include <hip/hip_runtime.h>
#include <stdint.h>
#include <math.h>

typedef __attribute__((ext_vector_type(8))) short short8;
typedef __attribute__((ext_vector_type(4))) float f32x4;

#define T_SEQ 2048
#define MROWS 4096

// ws byte offsets
#define OFF_XBF   ((size_t)0)          // 4096x1024 bf16 : 8 MB
#define OFF_WQ    ((size_t)8388608)    // 1024x1024 bf16 : 2 MB (WQ,WK,WV,WO contiguous)
#define OFF_WK    ((size_t)10485760)
#define OFF_WV    ((size_t)12582912)
#define OFF_WO    ((size_t)14680064)
#define OFF_Q     ((size_t)16777216)   // 4096x1024 bf16 (roped, *0.125)  (Q,K contiguous)
#define OFF_K     ((size_t)25165824)   // 4096x1024 bf16 (roped)
#define OFF_VT    ((size_t)33554432)   // [b][e][t] 2x1024x2048 bf16
#define OFF_ATT   ((size_t)41943040)   // 4096x1024 bf16
#define OFF_COS   ((size_t)50331648)   // 2048x32 f32
#define OFF_SIN   ((size_t)50593792)   // 2048x32 f32

__device__ __forceinline__ unsigned short f2bf(float f) {
  unsigned u = __float_as_uint(f);
  u += 0x7fffu + ((u >> 16) & 1u);
  return (unsigned short)(u >> 16);
}

__device__ __forceinline__ void gld_lds16(const void* g, void* l) {
  __builtin_amdgcn_global_load_lds(
      (__attribute__((address_space(1))) void*)(g),
      (__attribute__((address_space(3))) void*)(l), 16, 0, 0);
}

// ---------------- prep: bf16 conversions (vectorized) + rope tables ----------
__global__ void prep_kernel(const float* x, const float* wq, const float* wk,
                            const float* wv, const float* wo, char* ws) {
  const size_t NX4 = (size_t)MROWS * 1024 / 4;  // 1048576 float4s
  const size_t NW4 = (size_t)1024 * 1024 / 4;   // 262144 float4s
  const size_t NT = (size_t)T_SEQ * 32;         // 65536
  unsigned short* xb = (unsigned short*)(ws + OFF_XBF);
  unsigned short* wqb = (unsigned short*)(ws + OFF_WQ);
  unsigned short* wkb = (unsigned short*)(ws + OFF_WK);
  unsigned short* wvb = (unsigned short*)(ws + OFF_WV);
  unsigned short* wob = (unsigned short*)(ws + OFF_WO);
  float* cosb = (float*)(ws + OFF_COS);
  float* sinb = (float*)(ws + OFF_SIN);
  size_t nvec = NX4 + 4 * NW4;
  size_t total = nvec + NT;
  for (size_t i = (size_t)blockIdx.x * blockDim.x + threadIdx.x; i < total;
       i += (size_t)gridDim.x * blockDim.x) {
    if (i < nvec) {
      const float* src;
      unsigned short* dst;
      size_t e;
      if (i < NX4) {
        src = x; dst = xb; e = i * 4;
      } else {
        size_t j = i - NX4;
        int wsel = (int)(j / NW4);
        e = (j - (size_t)wsel * NW4) * 4;
        src = wsel == 0 ? wq : wsel == 1 ? wk : wsel == 2 ? wv : wo;
        dst = wsel == 0 ? wqb : wsel == 1 ? wkb : wsel == 2 ? wvb : wob;
      }
      float4 v = *(const float4*)(src + e);
      unsigned long long p =
          (unsigned long long)f2bf(v.x) |
          ((unsigned long long)f2bf(v.y) << 16) |
          ((unsigned long long)f2bf(v.z) << 32) |
          ((unsigned long long)f2bf(v.w) << 48);
      *(unsigned long long*)(dst + e) = p;
    } else {
      size_t j = i - nvec;
      int t = (int)(j >> 5), ii = (int)(j & 31);
      double th = exp(-(double)ii * (9.210340371976184 / 32.0));
      float ang = (float)t * (float)th;
      cosb[j] = cosf(ang);
      sinb[j] = sinf(ang);
    }
  }
}

// ---------------- fused QKV GEMM: [Q|K|V] = X @ [Wq;Wk;Wv]^T ----------------
// grid = 32 bm x 24 bn; bn 0-7 -> Q (rope, *0.125), 8-15 -> K (rope), 16-23 -> V^T
__global__ __launch_bounds__(256, 2) void gemm_qkv(
    const unsigned short* Abf, const unsigned short* Wall, unsigned short* qkout,
    unsigned short* vtout, const float* cosT, const float* sinT) {
  const int K = 1024;
  int bid = blockIdx.x;
  int bm = bid / 24, bn = bid % 24;
  int sel = bn >> 3, bnc = bn & 7;
  int tid = threadIdx.x;
  int l = tid & 63, w = tid >> 6;
  int wm = w >> 1, wn = w & 1;
  int g = l >> 4;

  __shared__ __align__(16) char ldsbuf[32768];  // [buf][A 8K | B 8K]

  auto stage = [&](int kt, int buf) {
    int base = buf * 16384;
#pragma unroll
    for (int i = 0; i < 2; ++i) {
      int p = (w * 2 + i) * 1024;
      int row = (p >> 6) + (l >> 2);
      int u = l & 3;
      const char* ga = (const char*)Abf +
          ((size_t)(bm * 128 + row) * K + (size_t)kt * 32) * 2 + u * 16;
      gld_lds16(ga, ldsbuf + base + p);
      const char* gb = (const char*)Wall +
          ((size_t)(bn * 128 + row) * K + (size_t)kt * 32) * 2 + u * 16;
      gld_lds16(gb, ldsbuf + base + 8192 + p);
    }
  };

  f32x4 acc[4][4] = {};
  stage(0, 0);
  const int nk = K / 32;
  for (int kt = 0; kt < nk; ++kt) {
    int buf = kt & 1;
    __syncthreads();
    if (kt + 1 < nk) stage(kt + 1, buf ^ 1);
    const char* Ab = ldsbuf + buf * 16384;
    const char* Bb = Ab + 8192;
    short8 af[4], bfr[4];
#pragma unroll
    for (int m = 0; m < 4; ++m)
      af[m] = *(const short8*)(Ab + (wm * 64 + m * 16 + (l & 15)) * 64 + g * 16);
#pragma unroll
    for (int n = 0; n < 4; ++n)
      bfr[n] = *(const short8*)(Bb + (wn * 64 + n * 16 + (l & 15)) * 64 + g * 16);
#pragma unroll
    for (int m = 0; m < 4; ++m)
#pragma unroll
      for (int n = 0; n < 4; ++n)
        acc[m][n] = __builtin_amdgcn_mfma_f32_16x16x32_bf16(af[m], bfr[n],
                                                            acc[m][n], 0, 0, 0);
    __syncthreads();
  }

  int row0 = bm * 128 + wm * 64;
  int col0 = bnc * 128 + wn * 64;
  if (sel < 2) {  // Q or K with fused RoPE
    float qscale = sel == 0 ? 0.125f : 1.0f;
    unsigned short* C = qkout + (size_t)sel * MROWS * 1024;
#pragma unroll
    for (int m = 0; m < 4; ++m)
#pragma unroll
      for (int n = 0; n < 2; ++n)
#pragma unroll
        for (int r = 0; r < 4; ++r) {
          int row = row0 + m * 16 + g * 4 + r;
          int t = row & (T_SEQ - 1);
          int d = n * 16 + (l & 15);  // 0..31 within head
          float c = cosT[t * 32 + d], s = sinT[t * 32 + d];
          float v0 = acc[m][n][r], v1 = acc[m][n + 2][r];
          C[(size_t)row * 1024 + col0 + d] = f2bf((v0 * c - v1 * s) * qscale);
          C[(size_t)row * 1024 + col0 + d + 32] = f2bf((v1 * c + v0 * s) * qscale);
        }
  } else {  // V^T[b][e][t]
    unsigned short* C = vtout;
#pragma unroll
    for (int m = 0; m < 4; ++m) {
      int rowb = row0 + m * 16 + g * 4;
      int bb = rowb >> 11, t0 = rowb & (T_SEQ - 1);
#pragma unroll
      for (int n = 0; n < 4; ++n) {
        int e = col0 + n * 16 + (l & 15);
        unsigned long long pv =
            (unsigned long long)f2bf(acc[m][n][0]) |
            ((unsigned long long)f2bf(acc[m][n][1]) << 16) |
            ((unsigned long long)f2bf(acc[m][n][2]) << 32) |
            ((unsigned long long)f2bf(acc[m][n][3]) << 48);
        *(unsigned long long*)(C + ((size_t)bb * 1024 + e) * T_SEQ + t0) = pv;
      }
    }
  }
}

// ---------------- Wo GEMM: out(f32) = ATT @ Wo^T ----------------
__global__ __launch_bounds__(256, 2) void gemm_wo(const unsigned short* Abf,
                                                  const unsigned short* Wbf,
                                                  float* out) {
  const int K = 1024, N = 1024;
  int bid = blockIdx.x;
  int bm = bid >> 3, bn = bid & 7;
  int tid = threadIdx.x;
  int l = tid & 63, w = tid >> 6;
  int wm = w >> 1, wn = w & 1;
  int g = l >> 4;

  __shared__ __align__(16) char ldsbuf[32768];

  auto stage = [&](int kt, int buf) {
    int base = buf * 16384;
#pragma unroll
    for (int i = 0; i < 2; ++i) {
      int p = (w * 2 + i) * 1024;
      int row = (p >> 6) + (l >> 2);
      int u = l & 3;
      const char* ga = (const char*)Abf +
          ((size_t)(bm * 128 + row) * K + (size_t)kt * 32) * 2 + u * 16;
      gld_lds16(ga, ldsbuf + base + p);
      const char* gb = (const char*)Wbf +
          ((size_t)(bn * 128 + row) * K + (size_t)kt * 32) * 2 + u * 16;
      gld_lds16(gb, ldsbuf + base + 8192 + p);
    }
  };

  f32x4 acc[4][4] = {};
  stage(0, 0);
  const int nk = K / 32;
  for (int kt = 0; kt < nk; ++kt) {
    int buf = kt & 1;
    __syncthreads();
    if (kt + 1 < nk) stage(kt + 1, buf ^ 1);
    const char* Ab = ldsbuf + buf * 16384;
    const char* Bb = Ab + 8192;
    short8 af[4], bfr[4];
#pragma unroll
    for (int m = 0; m < 4; ++m)
      af[m] = *(const short8*)(Ab + (wm * 64 + m * 16 + (l & 15)) * 64 + g * 16);
#pragma unroll
    for (int n = 0; n < 4; ++n)
      bfr[n] = *(const short8*)(Bb + (wn * 64 + n * 16 + (l & 15)) * 64 + g * 16);
#pragma unroll
    for (int m = 0; m < 4; ++m)
#pragma unroll
      for (int n = 0; n < 4; ++n)
        acc[m][n] = __builtin_amdgcn_mfma_f32_16x16x32_bf16(af[m], bfr[n],
                                                            acc[m][n], 0, 0, 0);
    __syncthreads();
  }

  int row0 = bm * 128 + wm * 64;
  int col0 = bn * 128 + wn * 64;
#pragma unroll
  for (int m = 0; m < 4; ++m)
#pragma unroll
    for (int n = 0; n < 4; ++n)
#pragma unroll
      for (int r = 0; r < 4; ++r)
        out[(size_t)(row0 + m * 16 + g * 4 + r) * N + col0 + n * 16 + (l & 15)] =
            acc[m][n][r];
}

// ---------------- flash attention: no LDS, no barriers, L2-direct frags -----
__global__ __launch_bounds__(256, 3) void attn_kernel(
    const unsigned short* Qbf, const unsigned short* Kbf,
    const unsigned short* VT, unsigned short* attn_out) {
  int bid = blockIdx.x;
  int qb = 31 - (bid >> 5);  // heavy-first launch order
  int bh = bid & 31;         // bh fast-varying: ~4 bh per XCD stay L2-hot
  int b = bh >> 4, h = bh & 15;
  int tid = threadIdx.x;
  int l = tid & 63, w = tid >> 6;
  int g = l >> 4;
  int qw = qb * 64 + w * 16;

  // Q B-fragments (scale folded in at GEMM): q row = qw + (l&15)
  short8 qf[2];
  {
    const char* qbase = (const char*)Qbf +
        ((size_t)(b * T_SEQ + qw + (l & 15)) * 1024 + h * 64) * 2 + g * 16;
    qf[0] = *(const short8*)qbase;
    qf[1] = *(const short8*)(qbase + 64);
  }

  // frag base pointers
  const char* kbase = (const char*)Kbf + ((size_t)b * T_SEQ * 1024 + h * 64) * 2;
  const char* vbase = (const char*)VT + ((size_t)(b * 1024 + h * 64)) * T_SEQ * 2;
  // per-lane fixed offsets
  const char* klane = kbase + (size_t)(l & 15) * 2048 + g * 16;
  const char* vlane = vbase + (size_t)(l & 15) * 4096 + g * 16;

  f32x4 o[4] = {};
  float m_run = -1e30f, l_run = 0.f;
  int nt = qb + 1;
  for (int kt = 0; kt < nt; ++kt) {
    // K fragments for this KV tile (A-operand rows kk, k-dim d)
    short8 kf[2][4];
#pragma unroll
    for (int ks = 0; ks < 2; ++ks)
#pragma unroll
      for (int f = 0; f < 4; ++f)
        kf[ks][f] = *(const short8*)(klane + (size_t)(kt * 64 + f * 16) * 2048 +
                                     ks * 64);

    // S^T = K . Q^T
    f32x4 st[4] = {};
#pragma unroll
    for (int ks = 0; ks < 2; ++ks)
#pragma unroll
      for (int f = 0; f < 4; ++f)
        st[f] = __builtin_amdgcn_mfma_f32_16x16x32_bf16(kf[ks][f], qf[ks],
                                                        st[f], 0, 0, 0);

    // V^T fragments issued early (used after softmax)
    short8 vf[2][4];
#pragma unroll
    for (int ks = 0; ks < 2; ++ks)
#pragma unroll
      for (int c = 0; c < 4; ++c)
        vf[ks][c] = *(const short8*)(vlane + (size_t)(c * 16) * 4096 + kt * 128 +
                                     ks * 64);

    if (kt == qb) {  // causal mask on diagonal tile
      int qg = qw + (l & 15);
#pragma unroll
      for (int f = 0; f < 4; ++f)
#pragma unroll
        for (int r = 0; r < 4; ++r) {
          int kk = kt * 64 + f * 16 + g * 4 + r;
          if (kk > qg) st[f][r] = -1e30f;
        }
    }

    // online softmax: q = l&15 is lane-local; reduce over g via xor 16/32
    float tm = -1e30f;
#pragma unroll
    for (int f = 0; f < 4; ++f)
#pragma unroll
      for (int r = 0; r < 4; ++r) tm = fmaxf(tm, st[f][r]);
    tm = fmaxf(tm, __shfl_xor(tm, 16));
    tm = fmaxf(tm, __shfl_xor(tm, 32));
    float m_new = fmaxf(m_run, tm);
    float factor = __expf(m_run - m_new);
    float pl[4][4];
    float ls = 0.f;
#pragma unroll
    for (int f = 0; f < 4; ++f)
#pragma unroll
      for (int r = 0; r < 4; ++r) {
        float pv = __expf(st[f][r] - m_new);
        pl[f][r] = pv;
        ls += pv;
      }
    ls += __shfl_xor(ls, 16);
    ls += __shfl_xor(ls, 32);
    l_run = l_run * factor + ls;
    m_run = m_new;

    // rescale O (O rows are q=g*4+r; factor lives at lane q)
#pragma unroll
    for (int r = 0; r < 4; ++r) {
      float fr = __shfl(factor, g * 4 + r, 64);
#pragma unroll
      for (int c = 0; c < 4; ++c) o[c][r] *= fr;
    }

    // P (S^T layout) -> A-frag layout via packed bf16 + shfl
    unsigned pk01[4], pk23[4];
#pragma unroll
    for (int f = 0; f < 4; ++f) {
      pk01[f] = (unsigned)f2bf(pl[f][0]) | ((unsigned)f2bf(pl[f][1]) << 16);
      pk23[f] = (unsigned)f2bf(pl[f][2]) | ((unsigned)f2bf(pl[f][3]) << 16);
    }
    int srcA = (l & 15) + 32 * (g & 1);
    int srcB = srcA + 16;
    int fsel = g >> 1;
    short8 pa[2];
#pragma unroll
    for (int ks = 0; ks < 2; ++ks) {
      unsigned a0 = __shfl(pk01[2 * ks], srcA, 64);
      unsigned a0b = __shfl(pk01[2 * ks + 1], srcA, 64);
      unsigned a1 = __shfl(pk23[2 * ks], srcA, 64);
      unsigned a1b = __shfl(pk23[2 * ks + 1], srcA, 64);
      unsigned b0 = __shfl(pk01[2 * ks], srcB, 64);
      unsigned b0b = __shfl(pk01[2 * ks + 1], srcB, 64);
      unsigned b1 = __shfl(pk23[2 * ks], srcB, 64);
      unsigned b1b = __shfl(pk23[2 * ks + 1], srcB, 64);
      union {
        unsigned u[4];
        short8 s8;
      } uu;
      uu.u[0] = fsel ? a0b : a0;
      uu.u[1] = fsel ? a1b : a1;
      uu.u[2] = fsel ? b0b : b0;
      uu.u[3] = fsel ? b1b : b1;
      pa[ks] = uu.s8;
    }

    // O += P . V
#pragma unroll
    for (int ks = 0; ks < 2; ++ks)
#pragma unroll
      for (int c = 0; c < 4; ++c)
        o[c] = __builtin_amdgcn_mfma_f32_16x16x32_bf16(pa[ks], vf[ks][c], o[c],
                                                       0, 0, 0);
  }

  float linv[4];
#pragma unroll
  for (int r = 0; r < 4; ++r) {
    float lr = __shfl(l_run, g * 4 + r, 64);
    linv[r] = 1.0f / lr;
  }
#pragma unroll
  for (int c = 0; c < 4; ++c)
#pragma unroll
    for (int r = 0; r < 4; ++r) {
      int qg = qw + g * 4 + r;
      int col = h * 64 + c * 16 + (l & 15);
      attn_out[(size_t)(b * T_SEQ + qg) * 1024 + col] = f2bf(o[c][r] * linv[r]);
    }
}

extern "C" void kernel_launch(void* const* d_in, const int* in_sizes, int n_in,
                              void* d_out, int out_size, void* d_ws,
                              size_t ws_size, hipStream_t stream) {
  const float* x = (const float*)d_in[0];
  const float* Wq = (const float*)d_in[1];
  const float* Wk = (const float*)d_in[2];
  const float* Wv = (const float*)d_in[3];
  const float* Wo = (const float*)d_in[4];
  char* ws = (char*)d_ws;

  unsigned short* xb = (unsigned short*)(ws + OFF_XBF);
  unsigned short* wall = (unsigned short*)(ws + OFF_WQ);  // WQ;WK;WV contiguous
  unsigned short* wob = (unsigned short*)(ws + OFF_WO);
  unsigned short* qbf = (unsigned short*)(ws + OFF_Q);    // Q;K contiguous
  unsigned short* kbf = (unsigned short*)(ws + OFF_K);
  unsigned short* vtb = (unsigned short*)(ws + OFF_VT);
  unsigned short* att = (unsigned short*)(ws + OFF_ATT);
  const float* cosT = (const float*)(ws + OFF_COS);
  const float* sinT = (const float*)(ws + OFF_SIN);

  prep_kernel<<<2048, 256, 0, stream>>>(x, Wq, Wk, Wv, Wo, ws);
  gemm_qkv<<<768, 256, 0, stream>>>(xb, wall, qbf, vtb, cosT, sinT);
  attn_kernel<<<1024, 256, 0, stream>>>(qbf, kbf, vtb, att);
  gemm_wo<<<256, 256, 0, stream>>>(att, wob, (float*)d_out);
}

// Round 3
// 121.675 us; speedup vs baseline: 1.7242x; 1.7242x over previous
//
#include <hip/hip_runtime.h>
#include <stdint.h>
#include <math.h>

typedef __attribute__((ext_vector_type(8))) short short8;
typedef __attribute__((ext_vector_type(4))) float f32x4;
typedef __attribute__((ext_vector_type(16))) float f32x16;

#define T_SEQ 2048
#define MROWS 4096
#define LOG2E 1.44269504088896f

// ws byte offsets
#define OFF_XBF   ((size_t)0)          // 4096x1024 bf16 : 8 MB
#define OFF_WQ    ((size_t)8388608)    // 1024x1024 bf16 : 2 MB (WQ,WK,WV,WO contiguous)
#define OFF_WK    ((size_t)10485760)
#define OFF_WV    ((size_t)12582912)
#define OFF_WO    ((size_t)14680064)
#define OFF_Q     ((size_t)16777216)   // 4096x1024 bf16 (roped, *0.125*log2e)
#define OFF_K     ((size_t)25165824)   // 4096x1024 bf16 (roped)
#define OFF_VT    ((size_t)33554432)   // [b][e][t] 2x1024x2048 bf16
#define OFF_ATT   ((size_t)41943040)   // 4096x1024 bf16
#define OFF_COS   ((size_t)50331648)   // 2048x32 f32
#define OFF_SIN   ((size_t)50593792)   // 2048x32 f32

__device__ __forceinline__ unsigned short f2bf(float f) {
  unsigned u = __float_as_uint(f);
  u += 0x7fffu + ((u >> 16) & 1u);
  return (unsigned short)(u >> 16);
}

__device__ __forceinline__ void gld_lds16(const void* g, void* l) {
  __builtin_amdgcn_global_load_lds(
      (__attribute__((address_space(1))) void*)(g),
      (__attribute__((address_space(3))) void*)(l), 16, 0, 0);
}

__device__ __forceinline__ unsigned cvt_pk_bf16(float lo, float hi) {
  unsigned r;
  asm("v_cvt_pk_bf16_f32 %0, %1, %2" : "=v"(r) : "v"(lo), "v"(hi));
  return r;
}

// ---------------- prep: bf16 conversions (vectorized) + rope tables ----------
__global__ void prep_kernel(const float* x, const float* wq, const float* wk,
                            const float* wv, const float* wo, char* ws) {
  const size_t NX4 = (size_t)MROWS * 1024 / 4;
  const size_t NW4 = (size_t)1024 * 1024 / 4;
  const size_t NT = (size_t)T_SEQ * 32;
  unsigned short* xb = (unsigned short*)(ws + OFF_XBF);
  unsigned short* wqb = (unsigned short*)(ws + OFF_WQ);
  unsigned short* wkb = (unsigned short*)(ws + OFF_WK);
  unsigned short* wvb = (unsigned short*)(ws + OFF_WV);
  unsigned short* wob = (unsigned short*)(ws + OFF_WO);
  float* cosb = (float*)(ws + OFF_COS);
  float* sinb = (float*)(ws + OFF_SIN);
  size_t nvec = NX4 + 4 * NW4;
  size_t total = nvec + NT;
  for (size_t i = (size_t)blockIdx.x * blockDim.x + threadIdx.x; i < total;
       i += (size_t)gridDim.x * blockDim.x) {
    if (i < nvec) {
      const float* src;
      unsigned short* dst;
      size_t e;
      if (i < NX4) {
        src = x; dst = xb; e = i * 4;
      } else {
        size_t j = i - NX4;
        int wsel = (int)(j / NW4);
        e = (j - (size_t)wsel * NW4) * 4;
        src = wsel == 0 ? wq : wsel == 1 ? wk : wsel == 2 ? wv : wo;
        dst = wsel == 0 ? wqb : wsel == 1 ? wkb : wsel == 2 ? wvb : wob;
      }
      float4 v = *(const float4*)(src + e);
      unsigned long long p =
          (unsigned long long)f2bf(v.x) |
          ((unsigned long long)f2bf(v.y) << 16) |
          ((unsigned long long)f2bf(v.z) << 32) |
          ((unsigned long long)f2bf(v.w) << 48);
      *(unsigned long long*)(dst + e) = p;
    } else {
      size_t j = i - nvec;
      int t = (int)(j >> 5), ii = (int)(j & 31);
      double th = exp(-(double)ii * (9.210340371976184 / 32.0));
      float ang = (float)t * (float)th;
      cosb[j] = cosf(ang);
      sinb[j] = sinf(ang);
    }
  }
}

// ---------------- fused QKV GEMM: [Q|K|V] = X @ [Wq;Wk;Wv]^T ----------------
__global__ __launch_bounds__(256, 2) void gemm_qkv(
    const unsigned short* Abf, const unsigned short* Wall, unsigned short* qkout,
    unsigned short* vtout, const float* cosT, const float* sinT) {
  const int K = 1024;
  int bid = blockIdx.x;
  int bm = bid / 24, bn = bid % 24;
  int sel = bn >> 3, bnc = bn & 7;
  int tid = threadIdx.x;
  int l = tid & 63, w = tid >> 6;
  int wm = w >> 1, wn = w & 1;
  int g = l >> 4;

  __shared__ __align__(16) char ldsbuf[32768];

  auto stage = [&](int kt, int buf) {
    int base = buf * 16384;
#pragma unroll
    for (int i = 0; i < 2; ++i) {
      int p = (w * 2 + i) * 1024;
      int row = (p >> 6) + (l >> 2);
      int u = l & 3;
      const char* ga = (const char*)Abf +
          ((size_t)(bm * 128 + row) * K + (size_t)kt * 32) * 2 + u * 16;
      gld_lds16(ga, ldsbuf + base + p);
      const char* gb = (const char*)Wall +
          ((size_t)(bn * 128 + row) * K + (size_t)kt * 32) * 2 + u * 16;
      gld_lds16(gb, ldsbuf + base + 8192 + p);
    }
  };

  f32x4 acc[4][4] = {};
  stage(0, 0);
  const int nk = K / 32;
  for (int kt = 0; kt < nk; ++kt) {
    int buf = kt & 1;
    __syncthreads();
    if (kt + 1 < nk) stage(kt + 1, buf ^ 1);
    const char* Ab = ldsbuf + buf * 16384;
    const char* Bb = Ab + 8192;
    short8 af[4], bfr[4];
#pragma unroll
    for (int m = 0; m < 4; ++m)
      af[m] = *(const short8*)(Ab + (wm * 64 + m * 16 + (l & 15)) * 64 + g * 16);
#pragma unroll
    for (int n = 0; n < 4; ++n)
      bfr[n] = *(const short8*)(Bb + (wn * 64 + n * 16 + (l & 15)) * 64 + g * 16);
#pragma unroll
    for (int m = 0; m < 4; ++m)
#pragma unroll
      for (int n = 0; n < 4; ++n)
        acc[m][n] = __builtin_amdgcn_mfma_f32_16x16x32_bf16(af[m], bfr[n],
                                                            acc[m][n], 0, 0, 0);
    __syncthreads();
  }

  int row0 = bm * 128 + wm * 64;
  int col0 = bnc * 128 + wn * 64;
  if (sel < 2) {  // Q or K with fused RoPE; Q also gets 0.125*log2e
    float qscale = sel == 0 ? 0.125f * LOG2E : 1.0f;
    unsigned short* C = qkout + (size_t)sel * MROWS * 1024;
#pragma unroll
    for (int m = 0; m < 4; ++m)
#pragma unroll
      for (int n = 0; n < 2; ++n)
#pragma unroll
        for (int r = 0; r < 4; ++r) {
          int row = row0 + m * 16 + g * 4 + r;
          int t = row & (T_SEQ - 1);
          int d = n * 16 + (l & 15);
          float c = cosT[t * 32 + d], s = sinT[t * 32 + d];
          float v0 = acc[m][n][r], v1 = acc[m][n + 2][r];
          C[(size_t)row * 1024 + col0 + d] = f2bf((v0 * c - v1 * s) * qscale);
          C[(size_t)row * 1024 + col0 + d + 32] = f2bf((v1 * c + v0 * s) * qscale);
        }
  } else {  // V^T[b][e][t]
    unsigned short* C = vtout;
#pragma unroll
    for (int m = 0; m < 4; ++m) {
      int rowb = row0 + m * 16 + g * 4;
      int bb = rowb >> 11, t0 = rowb & (T_SEQ - 1);
#pragma unroll
      for (int n = 0; n < 4; ++n) {
        int e = col0 + n * 16 + (l & 15);
        unsigned long long pv =
            (unsigned long long)f2bf(acc[m][n][0]) |
            ((unsigned long long)f2bf(acc[m][n][1]) << 16) |
            ((unsigned long long)f2bf(acc[m][n][2]) << 32) |
            ((unsigned long long)f2bf(acc[m][n][3]) << 48);
        *(unsigned long long*)(C + ((size_t)bb * 1024 + e) * T_SEQ + t0) = pv;
      }
    }
  }
}

// ---------------- Wo GEMM: out(f32) = ATT @ Wo^T ----------------
__global__ __launch_bounds__(256, 2) void gemm_wo(const unsigned short* Abf,
                                                  const unsigned short* Wbf,
                                                  float* out) {
  const int K = 1024, N = 1024;
  int bid = blockIdx.x;
  int bm = bid >> 3, bn = bid & 7;
  int tid = threadIdx.x;
  int l = tid & 63, w = tid >> 6;
  int wm = w >> 1, wn = w & 1;
  int g = l >> 4;

  __shared__ __align__(16) char ldsbuf[32768];

  auto stage = [&](int kt, int buf) {
    int base = buf * 16384;
#pragma unroll
    for (int i = 0; i < 2; ++i) {
      int p = (w * 2 + i) * 1024;
      int row = (p >> 6) + (l >> 2);
      int u = l & 3;
      const char* ga = (const char*)Abf +
          ((size_t)(bm * 128 + row) * K + (size_t)kt * 32) * 2 + u * 16;
      gld_lds16(ga, ldsbuf + base + p);
      const char* gb = (const char*)Wbf +
          ((size_t)(bn * 128 + row) * K + (size_t)kt * 32) * 2 + u * 16;
      gld_lds16(gb, ldsbuf + base + 8192 + p);
    }
  };

  f32x4 acc[4][4] = {};
  stage(0, 0);
  const int nk = K / 32;
  for (int kt = 0; kt < nk; ++kt) {
    int buf = kt & 1;
    __syncthreads();
    if (kt + 1 < nk) stage(kt + 1, buf ^ 1);
    const char* Ab = ldsbuf + buf * 16384;
    const char* Bb = Ab + 8192;
    short8 af[4], bfr[4];
#pragma unroll
    for (int m = 0; m < 4; ++m)
      af[m] = *(const short8*)(Ab + (wm * 64 + m * 16 + (l & 15)) * 64 + g * 16);
#pragma unroll
    for (int n = 0; n < 4; ++n)
      bfr[n] = *(const short8*)(Bb + (wn * 64 + n * 16 + (l & 15)) * 64 + g * 16);
#pragma unroll
    for (int m = 0; m < 4; ++m)
#pragma unroll
      for (int n = 0; n < 4; ++n)
        acc[m][n] = __builtin_amdgcn_mfma_f32_16x16x32_bf16(af[m], bfr[n],
                                                            acc[m][n], 0, 0, 0);
    __syncthreads();
  }

  int row0 = bm * 128 + wm * 64;
  int col0 = bn * 128 + wn * 8 * 16;
  col0 = bn * 128 + wn * 64;
#pragma unroll
  for (int m = 0; m < 4; ++m)
#pragma unroll
    for (int n = 0; n < 4; ++n)
#pragma unroll
      for (int r = 0; r < 4; ++r)
        out[(size_t)(row0 + m * 16 + g * 4 + r) * N + col0 + n * 16 + (l & 15)] =
            acc[m][n][r];
}

// ---------------- flash attention: 32x32 MFMA, lane-local softmax ----------
// Block: 4 warps x 32 q-rows = 128 q. KV tiles of 64, double-buffered LDS.
// S^T = K.Q^T (col=lane&31=q). PV: O^T = V^T.P^T, P^T built lane-locally;
// k-permutation compensated in V^T fragment addressing (slot-consistency).
__global__ __launch_bounds__(256, 2) void attn_kernel(
    const unsigned short* Qbf, const unsigned short* Kbf,
    const unsigned short* VT, unsigned short* att) {
  int bid = blockIdx.x;
  int bh = bid & 31;             // bh fast: XCD x sees bh = x mod 8 -> 2MB in L2
  int qt = 15 - (bid >> 5);      // heavy-first
  int b = bh >> 4, h = bh & 15;
  int tid = threadIdx.x;
  int l = tid & 63, w = tid >> 6;
  int q32 = l & 31, hi = l >> 5;
  int q0 = qt * 128;
  int q0w = q0 + w * 32;
  int nt = 2 * qt + 2;
  int ntw = (q0w + 95) >> 6;

  __shared__ __align__(16) char lds[2][16384];  // [buf][K 8K | V 8K]

  // Q B-fragments: slot(hi,j) = Q[q][ks*16 + hi*8 + j] (16B contiguous)
  short8 qf[4];
  {
    const char* qb = (const char*)Qbf +
        ((size_t)(b * T_SEQ + q0w + q32)) * 2048 + h * 128 + hi * 16;
#pragma unroll
    for (int ks = 0; ks < 4; ++ks) qf[ks] = *(const short8*)(qb + ks * 32);
  }

  auto stage = [&](int kt, int buf) {
    char* Kd = &lds[buf][0];
    char* Vd = &lds[buf][8192];
    int row = tid >> 3;          // 0..31
    int colb = (tid & 7) * 16;   // 0..112
#pragma unroll
    for (int r = 0; r < 2; ++r) {
      int d = row + r * 32;
      int sc = colb ^ ((d & 7) << 4);  // pre-swizzled SOURCE (rule #21)
      const char* gk = (const char*)Kbf +
          ((size_t)(b * T_SEQ + kt * 64 + d)) * 2048 + h * 128 + sc;
      gld_lds16(gk, Kd + d * 128 + colb);
      const char* gv = (const char*)VT +
          ((size_t)(b * 1024 + h * 64 + d)) * 4096 + kt * 128 + sc;
      gld_lds16(gv, Vd + d * 128 + colb);
    }
  };

  f32x16 o0 = {}, o1 = {};
  float m_run = -1e30f, l_run = 0.f;
  stage(0, 0);
  for (int kt = 0; kt < nt; ++kt) {
    int buf = kt & 1;
    __syncthreads();
    if (kt + 1 < nt) stage(kt + 1, buf ^ 1);
    if (kt < ntw) {
      const char* Kl = &lds[buf][0];
      const char* Vl = &lds[buf][8192];

      // ---- QK^T: S^T[kk][q], two 32-kk tiles ----
      f32x16 st0 = {}, st1 = {};
      __builtin_amdgcn_s_setprio(1);
#pragma unroll
      for (int ks = 0; ks < 4; ++ks) {
        int sc = (ks * 32 + hi * 16) ^ ((q32 & 7) << 4);
        short8 k0 = *(const short8*)(Kl + q32 * 128 + sc);
        short8 k1 = *(const short8*)(Kl + (q32 + 32) * 128 + sc);
        st0 = __builtin_amdgcn_mfma_f32_32x32x16_bf16(k0, qf[ks], st0, 0, 0, 0);
        st1 = __builtin_amdgcn_mfma_f32_32x32x16_bf16(k1, qf[ks], st1, 0, 0, 0);
      }
      __builtin_amdgcn_s_setprio(0);

      // causal mask (diagonal tiles only)
      if (kt * 64 + 63 > q0w) {
        int qa = q0w + q32;
#pragma unroll
        for (int r = 0; r < 16; ++r) {
          int kkb = kt * 64 + (r & 3) + 8 * (r >> 2) + 4 * hi;
          if (kkb > qa) st0[r] = -1e30f;
          if (kkb + 32 > qa) st1[r] = -1e30f;
        }
      }

      // ---- online softmax (scores pre-scaled by log2e; exp2 domain) ----
      float tm = -1e30f;
#pragma unroll
      for (int r = 0; r < 16; ++r) {
        tm = fmaxf(tm, st0[r]);
        tm = fmaxf(tm, st1[r]);
      }
      tm = fmaxf(tm, __shfl_xor(tm, 32));
      float m_new = fmaxf(m_run, tm);
      float fac = exp2f(m_run - m_new);
      float ls = 0.f;
#pragma unroll
      for (int r = 0; r < 16; ++r) {
        st0[r] = exp2f(st0[r] - m_new);
        st1[r] = exp2f(st1[r] - m_new);
        ls += st0[r] + st1[r];
      }
      ls += __shfl_xor(ls, 32);
      l_run = l_run * fac + ls;
      m_run = m_new;
#pragma unroll
      for (int r = 0; r < 16; ++r) {
        o0[r] *= fac;
        o1[r] *= fac;
      }

      // ---- pack P^T B-frags lane-locally: slot(hi,j) k = (j&3)+4hi+8(j>>2) ----
      short8 pb[4];
#pragma unroll
      for (int ks = 0; ks < 4; ++ks) {
        union { unsigned u[4]; short8 s8; } uu;
#pragma unroll
        for (int j = 0; j < 4; ++j) {
          int bse = (ks & 1) * 8 + 2 * j;
          float a = (ks & 2) ? st1[bse] : st0[bse];
          float c = (ks & 2) ? st1[bse + 1] : st0[bse + 1];
          uu.u[j] = cvt_pk_bf16(a, c);
        }
        pb[ks] = uu.s8;
      }

      // ---- PV: O^T[d][q] += V^T-frag . P^T ----
      __builtin_amdgcn_s_setprio(1);
#pragma unroll
      for (int ks = 0; ks < 4; ++ks) {
        int s = (q32 & 7) << 4;
        int cA = (ks * 32 + 8 * hi) ^ s;
        int cB = (ks * 32 + 16 + 8 * hi) ^ s;
#pragma unroll
        for (int c = 0; c < 2; ++c) {
          int dv = c * 32 + q32;
          union { unsigned long long u[2]; short8 s8; } vv;
          vv.u[0] = *(const unsigned long long*)(Vl + dv * 128 + cA);
          vv.u[1] = *(const unsigned long long*)(Vl + dv * 128 + cB);
          if (c == 0)
            o0 = __builtin_amdgcn_mfma_f32_32x32x16_bf16(vv.s8, pb[ks], o0, 0, 0, 0);
          else
            o1 = __builtin_amdgcn_mfma_f32_32x32x16_bf16(vv.s8, pb[ks], o1, 0, 0, 0);
        }
      }
      __builtin_amdgcn_s_setprio(0);
    }
  }

  // ---- epilogue: normalize, LDS transpose (XOR-swizzled), coalesced store ----
  float linv = 1.0f / l_run;
  __syncthreads();
  float* Ol = (float*)lds;
#pragma unroll
  for (int c = 0; c < 2; ++c)
#pragma unroll
    for (int r = 0; r < 16; ++r) {
      int d = c * 32 + (r & 3) + 8 * (r >> 2) + 4 * hi;
      float v = (c ? o1[r] : o0[r]) * linv;
      Ol[w * 2048 + q32 * 64 + (d ^ (q32 & 31))] = v;
    }
  __syncthreads();
#pragma unroll
  for (int i = 0; i < 4; ++i) {
    int idx = tid + i * 256;
    int row = idx >> 3;      // 0..127
    int seg = idx & 7;
    int q = row & 31, wq = row >> 5;
    unsigned short tmp[8];
#pragma unroll
    for (int j = 0; j < 8; ++j) {
      int d = seg * 8 + j;
      tmp[j] = f2bf(Ol[wq * 2048 + q * 64 + (d ^ (q & 31))]);
    }
    *(unsigned long long*)(att + ((size_t)(b * T_SEQ + q0 + row)) * 1024 +
                           h * 64 + seg * 8) =
        *(unsigned long long*)&tmp[0];
    *(unsigned long long*)(att + ((size_t)(b * T_SEQ + q0 + row)) * 1024 +
                           h * 64 + seg * 8 + 4) =
        *(unsigned long long*)&tmp[4];
  }
}

extern "C" void kernel_launch(void* const* d_in, const int* in_sizes, int n_in,
                              void* d_out, int out_size, void* d_ws,
                              size_t ws_size, hipStream_t stream) {
  const float* x = (const float*)d_in[0];
  const float* Wq = (const float*)d_in[1];
  const float* Wk = (const float*)d_in[2];
  const float* Wv = (const float*)d_in[3];
  const float* Wo = (const float*)d_in[4];
  char* ws = (char*)d_ws;

  unsigned short* xb = (unsigned short*)(ws + OFF_XBF);
  unsigned short* wall = (unsigned short*)(ws + OFF_WQ);
  unsigned short* wob = (unsigned short*)(ws + OFF_WO);
  unsigned short* qbf = (unsigned short*)(ws + OFF_Q);
  unsigned short* vtb = (unsigned short*)(ws + OFF_VT);
  unsigned short* att = (unsigned short*)(ws + OFF_ATT);
  unsigned short* kbf = (unsigned short*)(ws + OFF_K);
  const float* cosT = (const float*)(ws + OFF_COS);
  const float* sinT = (const float*)(ws + OFF_SIN);

  prep_kernel<<<2048, 256, 0, stream>>>(x, Wq, Wk, Wv, Wo, ws);
  gemm_qkv<<<768, 256, 0, stream>>>(xb, wall, qbf, vtb, cosT, sinT);
  attn_kernel<<<512, 256, 0, stream>>>(qbf, kbf, vtb, att);
  gemm_wo<<<256, 256, 0, stream>>>(att, wob, (float*)d_out);
}

// Round 4
// 120.543 us; speedup vs baseline: 1.7404x; 1.0094x over previous
//
#include <hip/hip_runtime.h>
#include <stdint.h>
#include <math.h>

typedef __attribute__((ext_vector_type(8))) short short8;
typedef __attribute__((ext_vector_type(4))) float f32x4;
typedef __attribute__((ext_vector_type(16))) float f32x16;

#define T_SEQ 2048
#define MROWS 4096
#define LOG2E 1.44269504088896f

// ws byte offsets
#define OFF_XBF   ((size_t)0)          // 4096x1024 bf16 : 8 MB
#define OFF_WQ    ((size_t)8388608)    // 1024x1024 bf16 : 2 MB (WQ,WK,WV,WO contiguous)
#define OFF_WK    ((size_t)10485760)
#define OFF_WV    ((size_t)12582912)
#define OFF_WO    ((size_t)14680064)
#define OFF_Q     ((size_t)16777216)   // 4096x1024 bf16 (roped, *0.125*log2e)
#define OFF_K     ((size_t)25165824)   // 4096x1024 bf16 (roped)
#define OFF_VT    ((size_t)33554432)   // [b][e][t] 2x1024x2048 bf16
#define OFF_ATT   ((size_t)41943040)   // 4096x1024 bf16
#define OFF_COS   ((size_t)50331648)   // 2048x32 f32
#define OFF_SIN   ((size_t)50593792)   // 2048x32 f32

__device__ __forceinline__ unsigned short f2bf(float f) {
  unsigned u = __float_as_uint(f);
  u += 0x7fffu + ((u >> 16) & 1u);
  return (unsigned short)(u >> 16);
}

__device__ __forceinline__ void gld_lds16(const void* g, void* l) {
  __builtin_amdgcn_global_load_lds(
      (__attribute__((address_space(1))) void*)(g),
      (__attribute__((address_space(3))) void*)(l), 16, 0, 0);
}

__device__ __forceinline__ unsigned cvt_pk_bf16(float lo, float hi) {
  unsigned r;
  asm("v_cvt_pk_bf16_f32 %0, %1, %2" : "=v"(r) : "v"(lo), "v"(hi));
  return r;
}

// ---------------- prep: bf16 conversions (vectorized) + rope tables ----------
__global__ void prep_kernel(const float* x, const float* wq, const float* wk,
                            const float* wv, const float* wo, char* ws) {
  const size_t NX4 = (size_t)MROWS * 1024 / 4;
  const size_t NW4 = (size_t)1024 * 1024 / 4;
  const size_t NT = (size_t)T_SEQ * 32;
  unsigned short* xb = (unsigned short*)(ws + OFF_XBF);
  unsigned short* wqb = (unsigned short*)(ws + OFF_WQ);
  unsigned short* wkb = (unsigned short*)(ws + OFF_WK);
  unsigned short* wvb = (unsigned short*)(ws + OFF_WV);
  unsigned short* wob = (unsigned short*)(ws + OFF_WO);
  float* cosb = (float*)(ws + OFF_COS);
  float* sinb = (float*)(ws + OFF_SIN);
  size_t nvec = NX4 + 4 * NW4;
  size_t total = nvec + NT;
  for (size_t i = (size_t)blockIdx.x * blockDim.x + threadIdx.x; i < total;
       i += (size_t)gridDim.x * blockDim.x) {
    if (i < nvec) {
      const float* src;
      unsigned short* dst;
      size_t e;
      if (i < NX4) {
        src = x; dst = xb; e = i * 4;
      } else {
        size_t j = i - NX4;
        int wsel = (int)(j / NW4);
        e = (j - (size_t)wsel * NW4) * 4;
        src = wsel == 0 ? wq : wsel == 1 ? wk : wsel == 2 ? wv : wo;
        dst = wsel == 0 ? wqb : wsel == 1 ? wkb : wsel == 2 ? wvb : wob;
      }
      float4 v = *(const float4*)(src + e);
      unsigned long long p =
          (unsigned long long)f2bf(v.x) |
          ((unsigned long long)f2bf(v.y) << 16) |
          ((unsigned long long)f2bf(v.z) << 32) |
          ((unsigned long long)f2bf(v.w) << 48);
      *(unsigned long long*)(dst + e) = p;
    } else {
      size_t j = i - nvec;
      int t = (int)(j >> 5), ii = (int)(j & 31);
      double th = exp(-(double)ii * (9.210340371976184 / 32.0));
      float ang = (float)t * (float)th;
      cosb[j] = cosf(ang);
      sinb[j] = sinf(ang);
    }
  }
}

// ---------------- fused QKV GEMM: [Q|K|V] = X @ [Wq;Wk;Wv]^T ----------------
__global__ __launch_bounds__(256, 2) void gemm_qkv(
    const unsigned short* Abf, const unsigned short* Wall, unsigned short* qkout,
    unsigned short* vtout, const float* cosT, const float* sinT) {
  const int K = 1024;
  int bid = blockIdx.x;
  int bm = bid / 24, bn = bid % 24;
  int sel = bn >> 3, bnc = bn & 7;
  int tid = threadIdx.x;
  int l = tid & 63, w = tid >> 6;
  int wm = w >> 1, wn = w & 1;
  int g = l >> 4;

  __shared__ __align__(16) char ldsbuf[32768];

  auto stage = [&](int kt, int buf) {
    int base = buf * 16384;
#pragma unroll
    for (int i = 0; i < 2; ++i) {
      int p = (w * 2 + i) * 1024;
      int row = (p >> 6) + (l >> 2);
      int u = l & 3;
      const char* ga = (const char*)Abf +
          ((size_t)(bm * 128 + row) * K + (size_t)kt * 32) * 2 + u * 16;
      gld_lds16(ga, ldsbuf + base + p);
      const char* gb = (const char*)Wall +
          ((size_t)(bn * 128 + row) * K + (size_t)kt * 32) * 2 + u * 16;
      gld_lds16(gb, ldsbuf + base + 8192 + p);
    }
  };

  f32x4 acc[4][4] = {};
  stage(0, 0);
  const int nk = K / 32;
  for (int kt = 0; kt < nk; ++kt) {
    int buf = kt & 1;
    __syncthreads();
    if (kt + 1 < nk) stage(kt + 1, buf ^ 1);
    const char* Ab = ldsbuf + buf * 16384;
    const char* Bb = Ab + 8192;
    short8 af[4], bfr[4];
#pragma unroll
    for (int m = 0; m < 4; ++m)
      af[m] = *(const short8*)(Ab + (wm * 64 + m * 16 + (l & 15)) * 64 + g * 16);
#pragma unroll
    for (int n = 0; n < 4; ++n)
      bfr[n] = *(const short8*)(Bb + (wn * 64 + n * 16 + (l & 15)) * 64 + g * 16);
#pragma unroll
    for (int m = 0; m < 4; ++m)
#pragma unroll
      for (int n = 0; n < 4; ++n)
        acc[m][n] = __builtin_amdgcn_mfma_f32_16x16x32_bf16(af[m], bfr[n],
                                                            acc[m][n], 0, 0, 0);
    __syncthreads();
  }

  int row0 = bm * 128 + wm * 64;
  int col0 = bnc * 128 + wn * 64;
  if (sel < 2) {  // Q or K with fused RoPE; Q also gets 0.125*log2e
    float qscale = sel == 0 ? 0.125f * LOG2E : 1.0f;
    unsigned short* C = qkout + (size_t)sel * MROWS * 1024;
#pragma unroll
    for (int m = 0; m < 4; ++m)
#pragma unroll
      for (int n = 0; n < 2; ++n)
#pragma unroll
        for (int r = 0; r < 4; ++r) {
          int row = row0 + m * 16 + g * 4 + r;
          int t = row & (T_SEQ - 1);
          int d = n * 16 + (l & 15);
          float c = cosT[t * 32 + d], s = sinT[t * 32 + d];
          float v0 = acc[m][n][r], v1 = acc[m][n + 2][r];
          C[(size_t)row * 1024 + col0 + d] = f2bf((v0 * c - v1 * s) * qscale);
          C[(size_t)row * 1024 + col0 + d + 32] = f2bf((v1 * c + v0 * s) * qscale);
        }
  } else {  // V^T[b][e][t]
    unsigned short* C = vtout;
#pragma unroll
    for (int m = 0; m < 4; ++m) {
      int rowb = row0 + m * 16 + g * 4;
      int bb = rowb >> 11, t0 = rowb & (T_SEQ - 1);
#pragma unroll
      for (int n = 0; n < 4; ++n) {
        int e = col0 + n * 16 + (l & 15);
        unsigned long long pv =
            (unsigned long long)f2bf(acc[m][n][0]) |
            ((unsigned long long)f2bf(acc[m][n][1]) << 16) |
            ((unsigned long long)f2bf(acc[m][n][2]) << 32) |
            ((unsigned long long)f2bf(acc[m][n][3]) << 48);
        *(unsigned long long*)(C + ((size_t)bb * 1024 + e) * T_SEQ + t0) = pv;
      }
    }
  }
}

// ---------------- Wo GEMM: out(f32) = ATT @ Wo^T ----------------
__global__ __launch_bounds__(256, 2) void gemm_wo(const unsigned short* Abf,
                                                  const unsigned short* Wbf,
                                                  float* out) {
  const int K = 1024, N = 1024;
  int bid = blockIdx.x;
  int bm = bid >> 3, bn = bid & 7;
  int tid = threadIdx.x;
  int l = tid & 63, w = tid >> 6;
  int wm = w >> 1, wn = w & 1;
  int g = l >> 4;

  __shared__ __align__(16) char ldsbuf[32768];

  auto stage = [&](int kt, int buf) {
    int base = buf * 16384;
#pragma unroll
    for (int i = 0; i < 2; ++i) {
      int p = (w * 2 + i) * 1024;
      int row = (p >> 6) + (l >> 2);
      int u = l & 3;
      const char* ga = (const char*)Abf +
          ((size_t)(bm * 128 + row) * K + (size_t)kt * 32) * 2 + u * 16;
      gld_lds16(ga, ldsbuf + base + p);
      const char* gb = (const char*)Wbf +
          ((size_t)(bn * 128 + row) * K + (size_t)kt * 32) * 2 + u * 16;
      gld_lds16(gb, ldsbuf + base + 8192 + p);
    }
  };

  f32x4 acc[4][4] = {};
  stage(0, 0);
  const int nk = K / 32;
  for (int kt = 0; kt < nk; ++kt) {
    int buf = kt & 1;
    __syncthreads();
    if (kt + 1 < nk) stage(kt + 1, buf ^ 1);
    const char* Ab = ldsbuf + buf * 16384;
    const char* Bb = Ab + 8192;
    short8 af[4], bfr[4];
#pragma unroll
    for (int m = 0; m < 4; ++m)
      af[m] = *(const short8*)(Ab + (wm * 64 + m * 16 + (l & 15)) * 64 + g * 16);
#pragma unroll
    for (int n = 0; n < 4; ++n)
      bfr[n] = *(const short8*)(Bb + (wn * 64 + n * 16 + (l & 15)) * 64 + g * 16);
#pragma unroll
    for (int m = 0; m < 4; ++m)
#pragma unroll
      for (int n = 0; n < 4; ++n)
        acc[m][n] = __builtin_amdgcn_mfma_f32_16x16x32_bf16(af[m], bfr[n],
                                                            acc[m][n], 0, 0, 0);
    __syncthreads();
  }

  int row0 = bm * 128 + wm * 64;
  int col0 = bn * 128 + wn * 64;
#pragma unroll
  for (int m = 0; m < 4; ++m)
#pragma unroll
    for (int n = 0; n < 4; ++n)
#pragma unroll
      for (int r = 0; r < 4; ++r)
        out[(size_t)(row0 + m * 16 + g * 4 + r) * N + col0 + n * 16 + (l & 15)] =
            acc[m][n][r];
}

// ---------------- flash attention: 32x32 MFMA, lane-local softmax ----------
// Balanced pairing: dispatch idx i and i+256 land on the same CU (512 blocks,
// round-robin period 256) -> pair qt=15-a with qt=a so every CU gets exactly
// 34 block-iterations. Defer-max (T13): skip O-rescale when max didn't grow.
__global__ __launch_bounds__(256, 2) void attn_kernel(
    const unsigned short* Qbf, const unsigned short* Kbf,
    const unsigned short* VT, unsigned short* att) {
  int bid = blockIdx.x;
  int half = bid >> 8;       // 0: heavy (qt 15..8), 1: light (qt 0..7)
  int idx = bid & 255;
  int bh = idx & 31;         // bh fast: XCD x sees bh = x mod 8 -> 2MB in L2
  int a = idx >> 5;          // 0..7
  int qt = half ? a : 15 - a;
  int b = bh >> 4, h = bh & 15;
  int tid = threadIdx.x;
  int l = tid & 63, w = tid >> 6;
  int q32 = l & 31, hi = l >> 5;
  int q0 = qt * 128;
  int q0w = q0 + w * 32;
  int nt = 2 * qt + 2;
  int ntw = (q0w + 95) >> 6;

  __shared__ __align__(16) char lds[2][16384];  // [buf][K 8K | V 8K]

  // Q B-fragments: slot(hi,j) = Q[q][ks*16 + hi*8 + j] (16B contiguous)
  short8 qf[4];
  {
    const char* qb = (const char*)Qbf +
        ((size_t)(b * T_SEQ + q0w + q32)) * 2048 + h * 128 + hi * 16;
#pragma unroll
    for (int ks = 0; ks < 4; ++ks) qf[ks] = *(const short8*)(qb + ks * 32);
  }

  auto stage = [&](int kt, int buf) {
    char* Kd = &lds[buf][0];
    char* Vd = &lds[buf][8192];
    int row = tid >> 3;          // 0..31
    int colb = (tid & 7) * 16;   // 0..112
#pragma unroll
    for (int r = 0; r < 2; ++r) {
      int d = row + r * 32;
      int sc = colb ^ ((d & 7) << 4);  // pre-swizzled SOURCE (rule #21)
      const char* gk = (const char*)Kbf +
          ((size_t)(b * T_SEQ + kt * 64 + d)) * 2048 + h * 128 + sc;
      gld_lds16(gk, Kd + d * 128 + colb);
      const char* gv = (const char*)VT +
          ((size_t)(b * 1024 + h * 64 + d)) * 4096 + kt * 128 + sc;
      gld_lds16(gv, Vd + d * 128 + colb);
    }
  };

  f32x16 o0 = {}, o1 = {};
  float m_run = -1e30f, l_run = 0.f;
  stage(0, 0);
  for (int kt = 0; kt < nt; ++kt) {
    int buf = kt & 1;
    __syncthreads();
    if (kt + 1 < nt) stage(kt + 1, buf ^ 1);
    if (kt < ntw) {
      const char* Kl = &lds[buf][0];
      const char* Vl = &lds[buf][8192];

      // ---- QK^T: S^T[kk][q], two 32-kk tiles ----
      f32x16 st0 = {}, st1 = {};
      __builtin_amdgcn_s_setprio(1);
#pragma unroll
      for (int ks = 0; ks < 4; ++ks) {
        int sc = (ks * 32 + hi * 16) ^ ((q32 & 7) << 4);
        short8 k0 = *(const short8*)(Kl + q32 * 128 + sc);
        short8 k1 = *(const short8*)(Kl + (q32 + 32) * 128 + sc);
        st0 = __builtin_amdgcn_mfma_f32_32x32x16_bf16(k0, qf[ks], st0, 0, 0, 0);
        st1 = __builtin_amdgcn_mfma_f32_32x32x16_bf16(k1, qf[ks], st1, 0, 0, 0);
      }
      __builtin_amdgcn_s_setprio(0);

      // causal mask (diagonal tiles only)
      if (kt * 64 + 63 > q0w) {
        int qa = q0w + q32;
#pragma unroll
        for (int r = 0; r < 16; ++r) {
          int kkb = kt * 64 + (r & 3) + 8 * (r >> 2) + 4 * hi;
          if (kkb > qa) st0[r] = -1e30f;
          if (kkb + 32 > qa) st1[r] = -1e30f;
        }
      }

      // ---- online softmax (exp2 domain; log2e folded into Q scale) ----
      float tm = -1e30f;
#pragma unroll
      for (int r = 0; r < 16; ++r) {
        tm = fmaxf(tm, st0[r]);
        tm = fmaxf(tm, st1[r]);
      }
      tm = fmaxf(tm, __shfl_xor(tm, 32));
      // defer-max: only rescale when some lane's max actually grew
      if (__any(tm > m_run)) {
        float m_new = fmaxf(m_run, tm);
        float fac = exp2f(m_run - m_new);
        l_run *= fac;
#pragma unroll
        for (int r = 0; r < 16; ++r) {
          o0[r] *= fac;
          o1[r] *= fac;
        }
        m_run = m_new;
      }
      float ls = 0.f;
#pragma unroll
      for (int r = 0; r < 16; ++r) {
        st0[r] = exp2f(st0[r] - m_run);
        st1[r] = exp2f(st1[r] - m_run);
        ls += st0[r] + st1[r];
      }
      ls += __shfl_xor(ls, 32);
      l_run += ls;

      // ---- pack P^T B-frags lane-locally: slot(hi,j) k = (j&3)+4hi+8(j>>2) ----
      short8 pb[4];
#pragma unroll
      for (int ks = 0; ks < 4; ++ks) {
        union { unsigned u[4]; short8 s8; } uu;
#pragma unroll
        for (int j = 0; j < 4; ++j) {
          int bse = (ks & 1) * 8 + 2 * j;
          float aa = (ks & 2) ? st1[bse] : st0[bse];
          float cc = (ks & 2) ? st1[bse + 1] : st0[bse + 1];
          uu.u[j] = cvt_pk_bf16(aa, cc);
        }
        pb[ks] = uu.s8;
      }

      // ---- PV: O^T[d][q] += V^T-frag . P^T ----
      __builtin_amdgcn_s_setprio(1);
#pragma unroll
      for (int ks = 0; ks < 4; ++ks) {
        int s = (q32 & 7) << 4;
        int cA = (ks * 32 + 8 * hi) ^ s;
        int cB = (ks * 32 + 16 + 8 * hi) ^ s;
#pragma unroll
        for (int c = 0; c < 2; ++c) {
          int dv = c * 32 + q32;
          union { unsigned long long u[2]; short8 s8; } vv;
          vv.u[0] = *(const unsigned long long*)(Vl + dv * 128 + cA);
          vv.u[1] = *(const unsigned long long*)(Vl + dv * 128 + cB);
          if (c == 0)
            o0 = __builtin_amdgcn_mfma_f32_32x32x16_bf16(vv.s8, pb[ks], o0, 0, 0, 0);
          else
            o1 = __builtin_amdgcn_mfma_f32_32x32x16_bf16(vv.s8, pb[ks], o1, 0, 0, 0);
        }
      }
      __builtin_amdgcn_s_setprio(0);
    }
  }

  // ---- epilogue: normalize, LDS transpose (XOR-swizzled), coalesced store ----
  float linv = 1.0f / l_run;
  __syncthreads();
  float* Ol = (float*)lds;
#pragma unroll
  for (int c = 0; c < 2; ++c)
#pragma unroll
    for (int r = 0; r < 16; ++r) {
      int d = c * 32 + (r & 3) + 8 * (r >> 2) + 4 * hi;
      float v = (c ? o1[r] : o0[r]) * linv;
      Ol[w * 2048 + q32 * 64 + (d ^ (q32 & 31))] = v;
    }
  __syncthreads();
#pragma unroll
  for (int i = 0; i < 4; ++i) {
    int idx2 = tid + i * 256;
    int row = idx2 >> 3;      // 0..127
    int seg = idx2 & 7;
    int q = row & 31, wq = row >> 5;
    unsigned short tmp[8];
#pragma unroll
    for (int j = 0; j < 8; ++j) {
      int d = seg * 8 + j;
      tmp[j] = f2bf(Ol[wq * 2048 + q * 64 + (d ^ (q & 31))]);
    }
    *(unsigned long long*)(att + ((size_t)(b * T_SEQ + q0 + row)) * 1024 +
                           h * 64 + seg * 8) =
        *(unsigned long long*)&tmp[0];
    *(unsigned long long*)(att + ((size_t)(b * T_SEQ + q0 + row)) * 1024 +
                           h * 64 + seg * 8 + 4) =
        *(unsigned long long*)&tmp[4];
  }
}

extern "C" void kernel_launch(void* const* d_in, const int* in_sizes, int n_in,
                              void* d_out, int out_size, void* d_ws,
                              size_t ws_size, hipStream_t stream) {
  const float* x = (const float*)d_in[0];
  const float* Wq = (const float*)d_in[1];
  const float* Wk = (const float*)d_in[2];
  const float* Wv = (const float*)d_in[3];
  const float* Wo = (const float*)d_in[4];
  char* ws = (char*)d_ws;

  unsigned short* xb = (unsigned short*)(ws + OFF_XBF);
  unsigned short* wall = (unsigned short*)(ws + OFF_WQ);
  unsigned short* wob = (unsigned short*)(ws + OFF_WO);
  unsigned short* qbf = (unsigned short*)(ws + OFF_Q);
  unsigned short* vtb = (unsigned short*)(ws + OFF_VT);
  unsigned short* att = (unsigned short*)(ws + OFF_ATT);
  unsigned short* kbf = (unsigned short*)(ws + OFF_K);
  const float* cosT = (const float*)(ws + OFF_COS);
  const float* sinT = (const float*)(ws + OFF_SIN);

  prep_kernel<<<2048, 256, 0, stream>>>(x, Wq, Wk, Wv, Wo, ws);
  gemm_qkv<<<768, 256, 0, stream>>>(xb, wall, qbf, vtb, cosT, sinT);
  attn_kernel<<<512, 256, 0, stream>>>(qbf, kbf, vtb, att);
  gemm_wo<<<256, 256, 0, stream>>>(att, wob, (float*)d_out);
}

// Round 5
// 115.516 us; speedup vs baseline: 1.8162x; 1.0435x over previous
//
#include <hip/hip_runtime.h>
#include <stdint.h>
#include <math.h>

typedef __attribute__((ext_vector_type(8))) short short8;
typedef __attribute__((ext_vector_type(4))) float f32x4;
typedef __attribute__((ext_vector_type(16))) float f32x16;

#define T_SEQ 2048
#define MROWS 4096
#define LOG2E 1.44269504088896f

// ws byte offsets
#define OFF_XBF   ((size_t)0)          // 4096x1024 bf16 : 8 MB
#define OFF_WQ    ((size_t)8388608)    // 1024x1024 bf16 : 2 MB (WQ,WK,WV,WO contiguous)
#define OFF_WK    ((size_t)10485760)
#define OFF_WV    ((size_t)12582912)
#define OFF_WO    ((size_t)14680064)
#define OFF_Q     ((size_t)16777216)   // 4096x1024 bf16 (roped, *0.125*log2e)
#define OFF_K     ((size_t)25165824)   // 4096x1024 bf16 (roped)
#define OFF_VT    ((size_t)33554432)   // [b][e][t] 2x1024x2048 bf16
#define OFF_ATT   ((size_t)41943040)   // 4096x1024 bf16
#define OFF_COS   ((size_t)50331648)   // 2048x32 f32
#define OFF_SIN   ((size_t)50593792)   // 2048x32 f32
// attn partials: reuse XBF (dead after gemm_qkv) + WQ (dead after gemm_qkv)
#define OFF_OPART ((size_t)0)          // 512 x 128 x 64 bf16 = 8388608 B exactly
#define OFF_ML    ((size_t)8388608)    // 512 x 128 x 2 f32 = 524288 B

__device__ __forceinline__ unsigned short f2bf(float f) {
  unsigned u = __float_as_uint(f);
  u += 0x7fffu + ((u >> 16) & 1u);
  return (unsigned short)(u >> 16);
}

__device__ __forceinline__ float bf2f(unsigned short u) {
  return __uint_as_float((unsigned)u << 16);
}

__device__ __forceinline__ void gld_lds16(const void* g, void* l) {
  __builtin_amdgcn_global_load_lds(
      (__attribute__((address_space(1))) void*)(g),
      (__attribute__((address_space(3))) void*)(l), 16, 0, 0);
}

__device__ __forceinline__ unsigned cvt_pk_bf16(float lo, float hi) {
  unsigned r;
  asm("v_cvt_pk_bf16_f32 %0, %1, %2" : "=v"(r) : "v"(lo), "v"(hi));
  return r;
}

// ---------------- prep: bf16 conversions (vectorized) + rope tables ----------
__global__ void prep_kernel(const float* x, const float* wq, const float* wk,
                            const float* wv, const float* wo, char* ws) {
  const size_t NX4 = (size_t)MROWS * 1024 / 4;
  const size_t NW4 = (size_t)1024 * 1024 / 4;
  const size_t NT = (size_t)T_SEQ * 32;
  unsigned short* xb = (unsigned short*)(ws + OFF_XBF);
  unsigned short* wqb = (unsigned short*)(ws + OFF_WQ);
  unsigned short* wkb = (unsigned short*)(ws + OFF_WK);
  unsigned short* wvb = (unsigned short*)(ws + OFF_WV);
  unsigned short* wob = (unsigned short*)(ws + OFF_WO);
  float* cosb = (float*)(ws + OFF_COS);
  float* sinb = (float*)(ws + OFF_SIN);
  size_t nvec = NX4 + 4 * NW4;
  size_t total = nvec + NT;
  for (size_t i = (size_t)blockIdx.x * blockDim.x + threadIdx.x; i < total;
       i += (size_t)gridDim.x * blockDim.x) {
    if (i < nvec) {
      const float* src;
      unsigned short* dst;
      size_t e;
      if (i < NX4) {
        src = x; dst = xb; e = i * 4;
      } else {
        size_t j = i - NX4;
        int wsel = (int)(j / NW4);
        e = (j - (size_t)wsel * NW4) * 4;
        src = wsel == 0 ? wq : wsel == 1 ? wk : wsel == 2 ? wv : wo;
        dst = wsel == 0 ? wqb : wsel == 1 ? wkb : wsel == 2 ? wvb : wob;
      }
      float4 v = *(const float4*)(src + e);
      unsigned long long p =
          (unsigned long long)f2bf(v.x) |
          ((unsigned long long)f2bf(v.y) << 16) |
          ((unsigned long long)f2bf(v.z) << 32) |
          ((unsigned long long)f2bf(v.w) << 48);
      *(unsigned long long*)(dst + e) = p;
    } else {
      size_t j = i - nvec;
      int t = (int)(j >> 5), ii = (int)(j & 31);
      double th = exp(-(double)ii * (9.210340371976184 / 32.0));
      float ang = (float)t * (float)th;
      cosb[j] = cosf(ang);
      sinb[j] = sinf(ang);
    }
  }
}

// ---------------- fused QKV GEMM: [Q|K|V] = X @ [Wq;Wk;Wv]^T ----------------
__global__ __launch_bounds__(256, 2) void gemm_qkv(
    const unsigned short* Abf, const unsigned short* Wall, unsigned short* qkout,
    unsigned short* vtout, const float* cosT, const float* sinT) {
  const int K = 1024;
  int bid = blockIdx.x;
  int bm = bid / 24, bn = bid % 24;
  int sel = bn >> 3, bnc = bn & 7;
  int tid = threadIdx.x;
  int l = tid & 63, w = tid >> 6;
  int wm = w >> 1, wn = w & 1;
  int g = l >> 4;

  __shared__ __align__(16) char ldsbuf[32768];

  auto stage = [&](int kt, int buf) {
    int base = buf * 16384;
#pragma unroll
    for (int i = 0; i < 2; ++i) {
      int p = (w * 2 + i) * 1024;
      int row = (p >> 6) + (l >> 2);
      int u = l & 3;
      const char* ga = (const char*)Abf +
          ((size_t)(bm * 128 + row) * K + (size_t)kt * 32) * 2 + u * 16;
      gld_lds16(ga, ldsbuf + base + p);
      const char* gb = (const char*)Wall +
          ((size_t)(bn * 128 + row) * K + (size_t)kt * 32) * 2 + u * 16;
      gld_lds16(gb, ldsbuf + base + 8192 + p);
    }
  };

  f32x4 acc[4][4] = {};
  stage(0, 0);
  const int nk = K / 32;
  for (int kt = 0; kt < nk; ++kt) {
    int buf = kt & 1;
    __syncthreads();
    if (kt + 1 < nk) stage(kt + 1, buf ^ 1);
    const char* Ab = ldsbuf + buf * 16384;
    const char* Bb = Ab + 8192;
    short8 af[4], bfr[4];
#pragma unroll
    for (int m = 0; m < 4; ++m)
      af[m] = *(const short8*)(Ab + (wm * 64 + m * 16 + (l & 15)) * 64 + g * 16);
#pragma unroll
    for (int n = 0; n < 4; ++n)
      bfr[n] = *(const short8*)(Bb + (wn * 64 + n * 16 + (l & 15)) * 64 + g * 16);
#pragma unroll
    for (int m = 0; m < 4; ++m)
#pragma unroll
      for (int n = 0; n < 4; ++n)
        acc[m][n] = __builtin_amdgcn_mfma_f32_16x16x32_bf16(af[m], bfr[n],
                                                            acc[m][n], 0, 0, 0);
    __syncthreads();
  }

  int row0 = bm * 128 + wm * 64;
  int col0 = bnc * 128 + wn * 64;
  if (sel < 2) {  // Q or K with fused RoPE; Q also gets 0.125*log2e
    float qscale = sel == 0 ? 0.125f * LOG2E : 1.0f;
    unsigned short* C = qkout + (size_t)sel * MROWS * 1024;
#pragma unroll
    for (int m = 0; m < 4; ++m)
#pragma unroll
      for (int n = 0; n < 2; ++n)
#pragma unroll
        for (int r = 0; r < 4; ++r) {
          int row = row0 + m * 16 + g * 4 + r;
          int t = row & (T_SEQ - 1);
          int d = n * 16 + (l & 15);
          float c = cosT[t * 32 + d], s = sinT[t * 32 + d];
          float v0 = acc[m][n][r], v1 = acc[m][n + 2][r];
          C[(size_t)row * 1024 + col0 + d] = f2bf((v0 * c - v1 * s) * qscale);
          C[(size_t)row * 1024 + col0 + d + 32] = f2bf((v1 * c + v0 * s) * qscale);
        }
  } else {  // V^T[b][e][t]
    unsigned short* C = vtout;
#pragma unroll
    for (int m = 0; m < 4; ++m) {
      int rowb = row0 + m * 16 + g * 4;
      int bb = rowb >> 11, t0 = rowb & (T_SEQ - 1);
#pragma unroll
      for (int n = 0; n < 4; ++n) {
        int e = col0 + n * 16 + (l & 15);
        unsigned long long pv =
            (unsigned long long)f2bf(acc[m][n][0]) |
            ((unsigned long long)f2bf(acc[m][n][1]) << 16) |
            ((unsigned long long)f2bf(acc[m][n][2]) << 32) |
            ((unsigned long long)f2bf(acc[m][n][3]) << 48);
        *(unsigned long long*)(C + ((size_t)bb * 1024 + e) * T_SEQ + t0) = pv;
      }
    }
  }
}

// ---------------- Wo GEMM: out(f32) = ATT @ Wo^T ----------------
__global__ __launch_bounds__(256, 2) void gemm_wo(const unsigned short* Abf,
                                                  const unsigned short* Wbf,
                                                  float* out) {
  const int K = 1024, N = 1024;
  int bid = blockIdx.x;
  int bm = bid >> 3, bn = bid & 7;
  int tid = threadIdx.x;
  int l = tid & 63, w = tid >> 6;
  int wm = w >> 1, wn = w & 1;
  int g = l >> 4;

  __shared__ __align__(16) char ldsbuf[32768];

  auto stage = [&](int kt, int buf) {
    int base = buf * 16384;
#pragma unroll
    for (int i = 0; i < 2; ++i) {
      int p = (w * 2 + i) * 1024;
      int row = (p >> 6) + (l >> 2);
      int u = l & 3;
      const char* ga = (const char*)Abf +
          ((size_t)(bm * 128 + row) * K + (size_t)kt * 32) * 2 + u * 16;
      gld_lds16(ga, ldsbuf + base + p);
      const char* gb = (const char*)Wbf +
          ((size_t)(bn * 128 + row) * K + (size_t)kt * 32) * 2 + u * 16;
      gld_lds16(gb, ldsbuf + base + 8192 + p);
    }
  };

  f32x4 acc[4][4] = {};
  stage(0, 0);
  const int nk = K / 32;
  for (int kt = 0; kt < nk; ++kt) {
    int buf = kt & 1;
    __syncthreads();
    if (kt + 1 < nk) stage(kt + 1, buf ^ 1);
    const char* Ab = ldsbuf + buf * 16384;
    const char* Bb = Ab + 8192;
    short8 af[4], bfr[4];
#pragma unroll
    for (int m = 0; m < 4; ++m)
      af[m] = *(const short8*)(Ab + (wm * 64 + m * 16 + (l & 15)) * 64 + g * 16);
#pragma unroll
    for (int n = 0; n < 4; ++n)
      bfr[n] = *(const short8*)(Bb + (wn * 64 + n * 16 + (l & 15)) * 64 + g * 16);
#pragma unroll
    for (int m = 0; m < 4; ++m)
#pragma unroll
      for (int n = 0; n < 4; ++n)
        acc[m][n] = __builtin_amdgcn_mfma_f32_16x16x32_bf16(af[m], bfr[n],
                                                            acc[m][n], 0, 0, 0);
    __syncthreads();
  }

  int row0 = bm * 128 + wm * 64;
  int col0 = bn * 128 + wn * 64;
#pragma unroll
  for (int m = 0; m < 4; ++m)
#pragma unroll
    for (int n = 0; n < 4; ++n)
#pragma unroll
      for (int r = 0; r < 4; ++r)
        out[(size_t)(row0 + m * 16 + g * 4 + r) * N + col0 + n * 16 + (l & 15)] =
            acc[m][n][r];
}

// ---------------- flash attention: 32x32 MFMA, KV-split, counted vmcnt -----
// Grid 768 = 3 bands x 256. Band 0/1: heavy qt=15-a halves s=0/1 (partials).
// Band 2: light qt=a, full range (direct normalized output).
// Per-CU triple (light a, heavy 15-a s0, heavy 15-a s1) = 34 tiles exactly.
// Pipeline: stage(next) -> vmcnt(4) -> barrier -> compute -> barrier: next-tile
// loads stay in flight across compute (no vmcnt(0) drain in steady state).
__global__ __launch_bounds__(256, 3) void attn_kernel(
    const unsigned short* Qbf, const unsigned short* Kbf,
    const unsigned short* VT, unsigned short* att,
    unsigned short* Opart, float* mlpart) {
  int bid = blockIdx.x;
  int band = bid >> 8;       // 0: heavy s=0, 1: heavy s=1, 2: light
  int c = bid & 255;
  int bh = c & 31;           // bh fast-varying: L2 locality per XCD
  int a = c >> 5;            // 0..7
  int b = bh >> 4, h = bh & 15;
  int qt, kt0, ntt, s;
  if (band == 2) {
    qt = a; s = 0; kt0 = 0; ntt = 2 * qt + 2;
  } else {
    qt = 15 - a; s = band;
    int ht = qt + 1;
    kt0 = s * ht; ntt = ht;
  }
  int tid = threadIdx.x;
  int l = tid & 63, w = tid >> 6;
  int q32 = l & 31, hi = l >> 5;
  int q0 = qt * 128;
  int q0w = q0 + w * 32;
  int ntw = ((q0w + 95) >> 6) - kt0;  // tiles this warp actually needs
  if (ntw > ntt) ntw = ntt;

  __shared__ __align__(16) char lds[2][16384];  // [buf][K 8K | V 8K]

  // Q B-fragments: slot(hi,j) = Q[q][ks*16 + hi*8 + j] (16B contiguous)
  short8 qf[4];
  {
    const char* qb = (const char*)Qbf +
        ((size_t)(b * T_SEQ + q0w + q32)) * 2048 + h * 128 + hi * 16;
#pragma unroll
    for (int ks = 0; ks < 4; ++ks) qf[ks] = *(const short8*)(qb + ks * 32);
  }
  // drain Q loads so vmcnt counting below tracks only gld_lds staging
  asm volatile("s_waitcnt vmcnt(0)" ::: "memory");

  auto stage = [&](int gt, int buf) {  // gt = global kv-tile index
    char* Kd = &lds[buf][0];
    char* Vd = &lds[buf][8192];
    int row = tid >> 3;          // 0..31
    int colb = (tid & 7) * 16;   // 0..112
#pragma unroll
    for (int r = 0; r < 2; ++r) {
      int d = row + r * 32;
      int sc = colb ^ ((d & 7) << 4);  // pre-swizzled SOURCE (rule #21)
      const char* gk = (const char*)Kbf +
          ((size_t)(b * T_SEQ + gt * 64 + d)) * 2048 + h * 128 + sc;
      gld_lds16(gk, Kd + d * 128 + colb);
      const char* gv = (const char*)VT +
          ((size_t)(b * 1024 + h * 64 + d)) * 4096 + gt * 128 + sc;
      gld_lds16(gv, Vd + d * 128 + colb);
    }
  };

  f32x16 o0 = {}, o1 = {};
  float m_run = -1e30f, l_run = 0.f;
  stage(kt0, 0);
  for (int kt = 0; kt < ntt; ++kt) {
    int buf = kt & 1;
    // issue next tile's 4 loads, then wait for current tile's 4 (leave 4 in flight)
    if (kt + 1 < ntt) {
      stage(kt0 + kt + 1, buf ^ 1);
      asm volatile("s_waitcnt vmcnt(4)" ::: "memory");
    } else {
      asm volatile("s_waitcnt vmcnt(0)" ::: "memory");
    }
    __builtin_amdgcn_s_barrier();      // all waves' tile-kt loads now in LDS
    __builtin_amdgcn_sched_barrier(0);
    if (kt < ntw) {
      int gt = kt0 + kt;
      const char* Kl = &lds[buf][0];
      const char* Vl = &lds[buf][8192];

      // ---- QK^T: S^T[kk][q], two 32-kk tiles ----
      f32x16 st0 = {}, st1 = {};
      __builtin_amdgcn_s_setprio(1);
#pragma unroll
      for (int ks = 0; ks < 4; ++ks) {
        int sc = (ks * 32 + hi * 16) ^ ((q32 & 7) << 4);
        short8 k0 = *(const short8*)(Kl + q32 * 128 + sc);
        short8 k1 = *(const short8*)(Kl + (q32 + 32) * 128 + sc);
        st0 = __builtin_amdgcn_mfma_f32_32x32x16_bf16(k0, qf[ks], st0, 0, 0, 0);
        st1 = __builtin_amdgcn_mfma_f32_32x32x16_bf16(k1, qf[ks], st1, 0, 0, 0);
      }
      __builtin_amdgcn_s_setprio(0);

      // causal mask (diagonal tiles only)
      if (gt * 64 + 63 > q0w) {
        int qa = q0w + q32;
#pragma unroll
        for (int r = 0; r < 16; ++r) {
          int kkb = gt * 64 + (r & 3) + 8 * (r >> 2) + 4 * hi;
          if (kkb > qa) st0[r] = -1e30f;
          if (kkb + 32 > qa) st1[r] = -1e30f;
        }
      }

      // ---- online softmax (exp2 domain; log2e folded into Q scale) ----
      float tm = -1e30f;
#pragma unroll
      for (int r = 0; r < 16; ++r) {
        tm = fmaxf(tm, st0[r]);
        tm = fmaxf(tm, st1[r]);
      }
      tm = fmaxf(tm, __shfl_xor(tm, 32));
      if (__any(tm > m_run)) {  // defer-max: rescale only when max grew
        float m_new = fmaxf(m_run, tm);
        float fac = exp2f(m_run - m_new);
        l_run *= fac;
#pragma unroll
        for (int r = 0; r < 16; ++r) {
          o0[r] *= fac;
          o1[r] *= fac;
        }
        m_run = m_new;
      }
      float ls = 0.f;
#pragma unroll
      for (int r = 0; r < 16; ++r) {
        st0[r] = exp2f(st0[r] - m_run);
        st1[r] = exp2f(st1[r] - m_run);
        ls += st0[r] + st1[r];
      }
      ls += __shfl_xor(ls, 32);
      l_run += ls;

      // ---- pack P^T B-frags lane-locally ----
      short8 pb[4];
#pragma unroll
      for (int ks = 0; ks < 4; ++ks) {
        union { unsigned u[4]; short8 s8; } uu;
#pragma unroll
        for (int j = 0; j < 4; ++j) {
          int bse = (ks & 1) * 8 + 2 * j;
          float aa = (ks & 2) ? st1[bse] : st0[bse];
          float cc = (ks & 2) ? st1[bse + 1] : st0[bse + 1];
          uu.u[j] = cvt_pk_bf16(aa, cc);
        }
        pb[ks] = uu.s8;
      }

      // ---- PV: O^T[d][q] += V^T-frag . P^T ----
      __builtin_amdgcn_s_setprio(1);
#pragma unroll
      for (int ks = 0; ks < 4; ++ks) {
        int sp = (q32 & 7) << 4;
        int cA = (ks * 32 + 8 * hi) ^ sp;
        int cB = (ks * 32 + 16 + 8 * hi) ^ sp;
#pragma unroll
        for (int cc = 0; cc < 2; ++cc) {
          int dv = cc * 32 + q32;
          union { unsigned long long u[2]; short8 s8; } vv;
          vv.u[0] = *(const unsigned long long*)(Vl + dv * 128 + cA);
          vv.u[1] = *(const unsigned long long*)(Vl + dv * 128 + cB);
          if (cc == 0)
            o0 = __builtin_amdgcn_mfma_f32_32x32x16_bf16(vv.s8, pb[ks], o0, 0, 0, 0);
          else
            o1 = __builtin_amdgcn_mfma_f32_32x32x16_bf16(vv.s8, pb[ks], o1, 0, 0, 0);
        }
      }
      __builtin_amdgcn_s_setprio(0);
    }
    __builtin_amdgcn_s_barrier();  // protect buf^1 from next iter's stage
  }

  // ---- epilogue: LDS transpose (XOR-swizzled), coalesced 16B stores ----
  float scale = (band == 2) ? (1.0f / l_run) : 1.0f;
  if (band != 2 && hi == 0) {  // write (m,l) partials, one lane per q-row
    float2 ml = {m_run, l_run};
    int pbi = ((bh << 3) + (qt - 8)) * 2 + s;
    *(float2*)(mlpart + ((size_t)pbi * 128 + w * 32 + q32) * 2) = ml;
  }
  __syncthreads();
  float* Ol = (float*)lds;
#pragma unroll
  for (int cc = 0; cc < 2; ++cc)
#pragma unroll
    for (int r = 0; r < 16; ++r) {
      int d = cc * 32 + (r & 3) + 8 * (r >> 2) + 4 * hi;
      float v = (cc ? o1[r] : o0[r]) * scale;
      Ol[w * 2048 + q32 * 64 + (d ^ (q32 & 31))] = v;
    }
  __syncthreads();
#pragma unroll
  for (int i = 0; i < 4; ++i) {
    int idx2 = tid + i * 256;
    int row = idx2 >> 3;      // 0..127
    int seg = idx2 & 7;
    int q = row & 31, wq = row >> 5;
    unsigned short tmp[8];
#pragma unroll
    for (int j = 0; j < 8; ++j) {
      int d = seg * 8 + j;
      tmp[j] = f2bf(Ol[wq * 2048 + q * 64 + (d ^ (q & 31))]);
    }
    if (band == 2) {
      *(unsigned long long*)(att + ((size_t)(b * T_SEQ + q0 + row)) * 1024 +
                             h * 64 + seg * 8) = *(unsigned long long*)&tmp[0];
      *(unsigned long long*)(att + ((size_t)(b * T_SEQ + q0 + row)) * 1024 +
                             h * 64 + seg * 8 + 4) = *(unsigned long long*)&tmp[4];
    } else {
      int pbi = ((bh << 3) + (qt - 8)) * 2 + s;
      *(unsigned long long*)(Opart + ((size_t)pbi * 128 + row) * 64 + seg * 8) =
          *(unsigned long long*)&tmp[0];
      *(unsigned long long*)(Opart + ((size_t)pbi * 128 + row) * 64 + seg * 8 + 4) =
          *(unsigned long long*)&tmp[4];
    }
  }
}

// ---------------- combine: merge the two KV-halves of heavy q-tiles --------
__global__ __launch_bounds__(256) void combine_kernel(
    const unsigned short* Opart, const float* mlpart, unsigned short* att) {
  int blk = blockIdx.x;      // 0..255 : (bh, j) with qt = 8 + j
  int bh = blk >> 3, j = blk & 7;
  int b = bh >> 4, h = bh & 15;
  int q0 = (8 + j) * 128;
  int pb0 = ((bh << 3) + j) * 2;
  const unsigned short* O0 = Opart + (size_t)pb0 * 128 * 64;
  const unsigned short* O1 = O0 + 128 * 64;
  const float* ml0 = mlpart + (size_t)pb0 * 256;
  const float* ml1 = ml0 + 256;
#pragma unroll
  for (int i = 0; i < 4; ++i) {
    int u = threadIdx.x + i * 256;
    int q = u >> 3, seg = u & 7;
    float m0 = ml0[q * 2], l0 = ml0[q * 2 + 1];
    float m1 = ml1[q * 2], l1 = ml1[q * 2 + 1];
    float m = fmaxf(m0, m1);
    float e0 = exp2f(m0 - m), e1 = exp2f(m1 - m);
    float inv = 1.0f / (l0 * e0 + l1 * e1);
    float s0 = e0 * inv, s1 = e1 * inv;
    short8 a = *(const short8*)(O0 + (size_t)q * 64 + seg * 8);
    short8 cvec = *(const short8*)(O1 + (size_t)q * 64 + seg * 8);
    union { unsigned short us[8]; short8 s8; } ov;
#pragma unroll
    for (int k = 0; k < 8; ++k)
      ov.us[k] = f2bf(bf2f((unsigned short)a[k]) * s0 +
                      bf2f((unsigned short)cvec[k]) * s1);
    *(short8*)(att + ((size_t)(b * T_SEQ + q0 + q)) * 1024 + h * 64 + seg * 8) =
        ov.s8;
  }
}

extern "C" void kernel_launch(void* const* d_in, const int* in_sizes, int n_in,
                              void* d_out, int out_size, void* d_ws,
                              size_t ws_size, hipStream_t stream) {
  const float* x = (const float*)d_in[0];
  const float* Wq = (const float*)d_in[1];
  const float* Wk = (const float*)d_in[2];
  const float* Wv = (const float*)d_in[3];
  const float* Wo = (const float*)d_in[4];
  char* ws = (char*)d_ws;

  unsigned short* xb = (unsigned short*)(ws + OFF_XBF);
  unsigned short* wall = (unsigned short*)(ws + OFF_WQ);
  unsigned short* wob = (unsigned short*)(ws + OFF_WO);
  unsigned short* qbf = (unsigned short*)(ws + OFF_Q);
  unsigned short* vtb = (unsigned short*)(ws + OFF_VT);
  unsigned short* att = (unsigned short*)(ws + OFF_ATT);
  unsigned short* kbf = (unsigned short*)(ws + OFF_K);
  unsigned short* opart = (unsigned short*)(ws + OFF_OPART);
  float* mlp = (float*)(ws + OFF_ML);
  const float* cosT = (const float*)(ws + OFF_COS);
  const float* sinT = (const float*)(ws + OFF_SIN);

  prep_kernel<<<2048, 256, 0, stream>>>(x, Wq, Wk, Wv, Wo, ws);
  gemm_qkv<<<768, 256, 0, stream>>>(xb, wall, qbf, vtb, cosT, sinT);
  attn_kernel<<<768, 256, 0, stream>>>(qbf, kbf, vtb, att, opart, mlp);
  combine_kernel<<<256, 256, 0, stream>>>(opart, mlp, att);
  gemm_wo<<<256, 256, 0, stream>>>(att, wob, (float*)d_out);
}